// Round 1
// baseline (230.568 us; speedup 1.0000x reference)
//
#include <hip/hip_runtime.h>

#define N_NODES 50000
#define N_EDGES 800000
#define DIM 96
#define FEAT_ELEMS (N_NODES * DIM)
#define NBLK 196   // ceil(50000/256)
#define EGRID 3125 // 800000/256
#define CGRID 4688 // ceil(FEAT_ELEMS/4/256)
#define GGRID 782  // ceil(50000/64)
#define APAD 104   // A-tile row pitch in ushorts (96 + 8 pad -> bank spread)

typedef __attribute__((ext_vector_type(8))) short short8;   // 8 bf16 (4 VGPRs)
typedef __attribute__((ext_vector_type(4))) float float4v;  // 4 fp32 acc

// ---------------------------------------------------------------------------
// bf16 helpers via raw bit ops
// ---------------------------------------------------------------------------
__device__ __forceinline__ float bf16_to_f32(unsigned short u) {
    unsigned int w = ((unsigned int)u) << 16;
    float f;
    __builtin_memcpy(&f, &w, 4);
    return f;
}
__device__ __forceinline__ unsigned short f32_to_bf16_rne(float f) {
    unsigned int w;
    __builtin_memcpy(&w, &f, 4);
    unsigned int r = (w + 0x7FFFu + ((w >> 16) & 1u)) >> 16;
    return (unsigned short)r;
}
__device__ __forceinline__ unsigned int pack_bf16x2(float lo, float hi) {
    return (unsigned int)f32_to_bf16_rne(lo) | ((unsigned int)f32_to_bf16_rne(hi) << 16);
}

__device__ __forceinline__ int edge_at(const void* ep, int is64, int idx) {
    if (is64) return (int)((const long long*)ep)[idx];
    return ((const int*)ep)[idx];
}

// ---------------------------------------------------------------------------
// prolog: blocks [0,NBLK) zero cnt; block NBLK detects edge dtype (int64 =>
// odd 32-bit words all zero => flagE=1); block NBLK+1 detects float dtype of
// x (bf16 => bits14..7 is a N(0,1) bf16 exponent in [100,135] => flagF=1).
// ---------------------------------------------------------------------------
__global__ __launch_bounds__(256) void prolog_kernel(const unsigned int* edges,
                                                     const unsigned int* x,
                                                     int* flagE, int* flagF, int* cnt) {
    __shared__ unsigned int sh[256];
    int t = threadIdx.x;
    int b = blockIdx.x;
    if (b < NBLK) {
        int i = b * 256 + t;
        if (i < N_NODES) cnt[i] = 0;
        return;
    }
    if (b == NBLK) {
        if (t < 64) {
            unsigned int acc = 0;
            for (int k = 0; k < 4; ++k) {
                int idx = t * 4 + k;           // 0..255
                int pos = 1 + 2 * idx * 3109;  // odd words, max 1,585,591 < 1.6M
                acc |= edges[pos];
            }
            sh[t] = acc;
        }
        __syncthreads();
        if (t == 0) {
            unsigned int a = 0;
            for (int i = 0; i < 64; ++i) a |= sh[i];
            *flagE = (a == 0u) ? 1 : 0;
        }
        return;
    }
    // b == NBLK+1: feature dtype
    unsigned int w = x[t * 9000];  // max 2,295,000 < 2.4M words (bf16 interp)
    unsigned int e = (w >> 7) & 0xFFu;
    sh[t] = (e >= 100u && e <= 135u) ? 1u : 0u;
    __syncthreads();
    if (t == 0) {
        int c = 0;
        for (int i = 0; i < 256; ++i) c += (int)sh[i];
        *flagF = (c >= 128) ? 1 : 0;
    }
}

// ---------------------------------------------------------------------------
// fused: blocks [0,EGRID) do count+compact+rank; blocks [EGRID, EGRID+CGRID)
// convert features to bf16. Both depend only on prolog output.
// ---------------------------------------------------------------------------
__global__ __launch_bounds__(256) void count_convert_kernel(const void* __restrict__ edges,
                                                            const void* __restrict__ x,
                                                            const int* __restrict__ flagE,
                                                            const int* __restrict__ flagF,
                                                            int* __restrict__ cnt,
                                                            unsigned short* __restrict__ srcu,
                                                            unsigned short* __restrict__ dstu,
                                                            unsigned short* __restrict__ rank,
                                                            unsigned short* __restrict__ xb) {
    int b = blockIdx.x;
    if (b < EGRID) {
        int e = b * 256 + threadIdx.x;  // EGRID*256 == N_EDGES exactly
        int is64 = *flagE;
        int s = edge_at(edges, is64, e);
        int d = edge_at(edges, is64, N_EDGES + e);
        srcu[e] = (unsigned short)s;
        dstu[e] = (unsigned short)d;
        rank[e] = (unsigned short)atomicAdd(&cnt[d], 1);
        return;
    }
    int i4 = ((b - EGRID) * 256 + threadIdx.x) * 4;
    if (i4 >= FEAT_ELEMS) return;
    int isbf16 = *flagF;
    ushort4 o;
    if (isbf16) {
        o = *(const ushort4*)((const unsigned short*)x + i4);
    } else {
        float4 v = *(const float4*)((const float*)x + i4);
        o.x = f32_to_bf16_rne(v.x);
        o.y = f32_to_bf16_rne(v.y);
        o.z = f32_to_bf16_rne(v.z);
        o.w = f32_to_bf16_rne(v.w);
    }
    *(ushort4*)(xb + i4) = o;
}

// ---------------------------------------------------------------------------
// scan phase 1: per-block sums of cnt
// ---------------------------------------------------------------------------
__global__ __launch_bounds__(256) void scan_blocksum_kernel(const int* cnt, int* blockSums) {
    __shared__ int sh[256];
    int i = blockIdx.x * 256 + threadIdx.x;
    sh[threadIdx.x] = (i < N_NODES) ? cnt[i] : 0;
    __syncthreads();
    for (int off = 128; off > 0; off >>= 1) {
        if (threadIdx.x < off) sh[threadIdx.x] += sh[threadIdx.x + off];
        __syncthreads();
    }
    if (threadIdx.x == 0) blockSums[blockIdx.x] = sh[0];
}

// ---------------------------------------------------------------------------
// scan phase 2 (merged offsets+apply): every block redundantly scans the 196
// block sums in LDS (cheap), derives its own exclusive offset, then scans its
// 256 cnt entries -> row_ptr (+ dinv). Block 0 thread 0 writes the total.
// ---------------------------------------------------------------------------
__global__ __launch_bounds__(256) void scan_apply_kernel(const int* __restrict__ cnt,
                                                         const int* __restrict__ blockSums,
                                                         int* __restrict__ row_ptr,
                                                         float* __restrict__ dinv) {
    __shared__ int sb[256];
    __shared__ int sh[256];
    int t = threadIdx.x;
    sb[t] = (t < NBLK) ? blockSums[t] : 0;
    __syncthreads();
    for (int off = 1; off < 256; off <<= 1) {
        int u = (t >= off) ? sb[t - off] : 0;
        __syncthreads();
        sb[t] += u;
        __syncthreads();
    }
    int b = blockIdx.x;
    int blockOff = (b == 0) ? 0 : sb[b - 1];  // exclusive prefix of this block
    if (b == 0 && t == 0) row_ptr[N_NODES] = sb[NBLK - 1];

    int i = b * 256 + t;
    int c = (i < N_NODES) ? cnt[i] : 0;
    sh[t] = c;
    __syncthreads();
    for (int off = 1; off < 256; off <<= 1) {
        int u = (t >= off) ? sh[t - off] : 0;
        __syncthreads();
        sh[t] += u;
        __syncthreads();
    }
    if (i < N_NODES) {
        row_ptr[i] = sh[t] - c + blockOff;
        dinv[i]    = rsqrtf((float)(c + 1));  // +1 self-loop
    }
}

// ---------------------------------------------------------------------------
// fill (rank-based direct scatter, NO atomics)
// ---------------------------------------------------------------------------
__global__ __launch_bounds__(256) void fill_direct_kernel(const unsigned short* __restrict__ dstu,
                                                          const unsigned short* __restrict__ srcu,
                                                          const unsigned short* __restrict__ rank,
                                                          const int* __restrict__ row_ptr,
                                                          unsigned short* __restrict__ csr_src) {
    int e = blockIdx.x * 256 + threadIdx.x;
    if (e >= N_EDGES) return;
    int d = dstu[e];
    int pos = row_ptr[d] + (int)rank[e];
    csr_src[pos] = srcu[e];
}

// ---------------------------------------------------------------------------
// FUSED layer: gather-aggregate (bf16 feat, fp32 accum) into an LDS A-tile,
// then MFMA GEMM + bias + ReLU, all in one kernel. 256 thr/block = 64 rows.
//
// Phase 1 (no sync needed before it): all threads build Wsw (B-frag-swizzled
// W) directly from global. Frag f=(kt*6+nt)*64+lane holds
// W[kt*32+(lane>>4)*8+j][nt*16+(lane&15)], j=0..7 (verified layouts
// learn_hip m89/m91/m120).
// Phase 2: 16 lanes/node gather; each 16-lane group does 4 nodes; fp32
// accum -> bf16 packed into Atile[64][APAD] (APAD=104 breaks the 192B-row
// bank alias: word stride 52 -> (20*ln)%32 spread).
// One __syncthreads, then:
// Phase 3: mfma_f32_16x16x32_bf16, K=3x32; A-frag = ds_read_b128 from Atile.
// C/D: col=lane&15, row=(lane>>4)*4+reg.
// outMode: 0=fp32, 1=bf16, 2=follow flagF
// ---------------------------------------------------------------------------
__global__ __launch_bounds__(256) void fused_layer_kernel(const unsigned short* __restrict__ feat,
                                                          const int* __restrict__ row_ptr,
                                                          const unsigned short* __restrict__ csr_src,
                                                          const float* __restrict__ dinv,
                                                          const void* __restrict__ W,
                                                          const void* __restrict__ bias,
                                                          const int* __restrict__ flagF,
                                                          void* __restrict__ out, int outMode) {
    __shared__ __align__(16) unsigned short Wsw[3 * 6 * 64 * 8];  // 18432 B
    __shared__ __align__(16) unsigned short Atile[64 * APAD];     // 13312 B

    int t = threadIdx.x;
    int wBf16 = *flagF;
    int outBf16 = (outMode == 2) ? wBf16 : outMode;

    // ---- phase 1: build B-fragment-swizzled W straight from global ----
    for (int f = t; f < 1152; f += 256) {
        int kt = f / 384;
        int rem = f - kt * 384;
        int nt = rem >> 6;
        int ln64 = rem & 63;
        int q = ln64 >> 4, ln = ln64 & 15;
        int k0 = kt * 32 + q * 8;
        int n = nt * 16 + ln;
        unsigned short e[8];
        if (wBf16) {
            const unsigned short* Wh = (const unsigned short*)W;
            #pragma unroll
            for (int j = 0; j < 8; ++j) e[j] = Wh[(k0 + j) * DIM + n];
        } else {
            const float* Wf = (const float*)W;
            #pragma unroll
            for (int j = 0; j < 8; ++j) e[j] = f32_to_bf16_rne(Wf[(k0 + j) * DIM + n]);
        }
        uint4 pk;
        pk.x = (unsigned int)e[0] | ((unsigned int)e[1] << 16);
        pk.y = (unsigned int)e[2] | ((unsigned int)e[3] << 16);
        pk.z = (unsigned int)e[4] | ((unsigned int)e[5] << 16);
        pk.w = (unsigned int)e[6] | ((unsigned int)e[7] << 16);
        *(uint4*)&Wsw[f * 8] = pk;
    }

    // ---- phase 2: gather 64 nodes into Atile (16 lanes/node, 4 nodes/grp) --
    int m0 = blockIdx.x * 64;
    int grp = t >> 4;
    int l = t & 15;
    for (int p = 0; p < 4; ++p) {
        int r = grp * 4 + p;  // local row 0..63
        int g = m0 + r;
        float a0 = 0.f, a1 = 0.f, a2 = 0.f, a3 = 0.f, a4 = 0.f, a5 = 0.f;
        if (g < N_NODES) {
            float di = dinv[g];
            int gb = g * DIM + l * 2;
            ushort2 sv0 = *(const ushort2*)&feat[gb];
            ushort2 sv1 = *(const ushort2*)&feat[gb + 32];
            ushort2 sv2 = *(const ushort2*)&feat[gb + 64];
            float wself = di * di;
            a0 = wself * bf16_to_f32(sv0.x); a1 = wself * bf16_to_f32(sv0.y);
            a2 = wself * bf16_to_f32(sv1.x); a3 = wself * bf16_to_f32(sv1.y);
            a4 = wself * bf16_to_f32(sv2.x); a5 = wself * bf16_to_f32(sv2.y);
            int e = row_ptr[g], e1 = row_ptr[g + 1];
            for (; e + 2 <= e1; e += 2) {
                int s0 = csr_src[e];
                int s1 = csr_src[e + 1];
                float w0 = dinv[s0] * di;
                float w1 = dinv[s1] * di;
                int b0 = s0 * DIM + l * 2;
                int b1 = s1 * DIM + l * 2;
                ushort2 p0 = *(const ushort2*)&feat[b0];
                ushort2 p1 = *(const ushort2*)&feat[b0 + 32];
                ushort2 p2 = *(const ushort2*)&feat[b0 + 64];
                ushort2 q0 = *(const ushort2*)&feat[b1];
                ushort2 q1 = *(const ushort2*)&feat[b1 + 32];
                ushort2 q2 = *(const ushort2*)&feat[b1 + 64];
                a0 = fmaf(w0, bf16_to_f32(p0.x), a0);  a1 = fmaf(w0, bf16_to_f32(p0.y), a1);
                a2 = fmaf(w0, bf16_to_f32(p1.x), a2);  a3 = fmaf(w0, bf16_to_f32(p1.y), a3);
                a4 = fmaf(w0, bf16_to_f32(p2.x), a4);  a5 = fmaf(w0, bf16_to_f32(p2.y), a5);
                a0 = fmaf(w1, bf16_to_f32(q0.x), a0);  a1 = fmaf(w1, bf16_to_f32(q0.y), a1);
                a2 = fmaf(w1, bf16_to_f32(q1.x), a2);  a3 = fmaf(w1, bf16_to_f32(q1.y), a3);
                a4 = fmaf(w1, bf16_to_f32(q2.x), a4);  a5 = fmaf(w1, bf16_to_f32(q2.y), a5);
            }
            if (e < e1) {
                int s = csr_src[e];
                float w = dinv[s] * di;
                int b0 = s * DIM + l * 2;
                ushort2 p0 = *(const ushort2*)&feat[b0];
                ushort2 p1 = *(const ushort2*)&feat[b0 + 32];
                ushort2 p2 = *(const ushort2*)&feat[b0 + 64];
                a0 = fmaf(w, bf16_to_f32(p0.x), a0);  a1 = fmaf(w, bf16_to_f32(p0.y), a1);
                a2 = fmaf(w, bf16_to_f32(p1.x), a2);  a3 = fmaf(w, bf16_to_f32(p1.y), a3);
                a4 = fmaf(w, bf16_to_f32(p2.x), a4);  a5 = fmaf(w, bf16_to_f32(p2.y), a5);
            }
        }
        int ab = r * APAD + l * 2;
        *(unsigned int*)&Atile[ab]      = pack_bf16x2(a0, a1);
        *(unsigned int*)&Atile[ab + 32] = pack_bf16x2(a2, a3);
        *(unsigned int*)&Atile[ab + 64] = pack_bf16x2(a4, a5);
    }
    __syncthreads();

    // ---- phase 3: MFMA GEMM ----
    int wave = t >> 6;
    int lane = t & 63;
    int quad = lane >> 4, ln = lane & 15;
    int rloc = wave * 16 + ln;  // local A row this lane supplies

    float4v acc[6];
    #pragma unroll
    for (int nt = 0; nt < 6; ++nt) acc[nt] = (float4v){0.f, 0.f, 0.f, 0.f};

    #pragma unroll
    for (int kt = 0; kt < 3; ++kt) {
        short8 af = *(const short8*)&Atile[rloc * APAD + kt * 32 + quad * 8];
        #pragma unroll
        for (int nt = 0; nt < 6; ++nt) {
            short8 bf = *(const short8*)&Wsw[((kt * 6 + nt) * 64 + lane) * 8];
            acc[nt] = __builtin_amdgcn_mfma_f32_16x16x32_bf16(af, bf, acc[nt], 0, 0, 0);
        }
    }

    // ---- epilogue: C/D col = ln, row = quad*4 + reg; bias from global ----
    #pragma unroll
    for (int nt = 0; nt < 6; ++nt) {
        int n = nt * 16 + ln;
        float bv = wBf16 ? bf16_to_f32(((const unsigned short*)bias)[n])
                         : ((const float*)bias)[n];
        #pragma unroll
        for (int reg = 0; reg < 4; ++reg) {
            int row = m0 + wave * 16 + quad * 4 + reg;
            if (row >= N_NODES) continue;
            float v = fmaxf(acc[nt][reg] + bv, 0.0f);
            if (outBf16) ((unsigned short*)out)[row * DIM + n] = f32_to_bf16_rne(v);
            else         ((float*)out)[row * DIM + n] = v;
        }
    }
}

// ---------------------------------------------------------------------------
extern "C" void kernel_launch(void* const* d_in, const int* in_sizes, int n_in,
                              void* d_out, int out_size, void* d_ws, size_t ws_size,
                              hipStream_t stream) {
    const void* x  = d_in[0];
    const void* ei = d_in[1];
    const void* W1 = d_in[2];
    const void* b1 = d_in[3];
    const void* W2 = d_in[4];
    const void* b2 = d_in[5];

    char* base = (char*)d_ws;
    size_t off = 0;
    auto carve = [&](size_t bytes) -> void* {
        void* p = base + off;
        off += (bytes + 255) & ~(size_t)255;
        return p;
    };
    int*            flagE     = (int*)carve(4);
    int*            flagF     = (int*)carve(4);
    int*            cnt       = (int*)carve((size_t)N_NODES * 4);
    int*            row_ptr   = (int*)carve((size_t)(N_NODES + 1) * 4);
    float*          dinv      = (float*)carve((size_t)N_NODES * 4);
    int*            blockSums = (int*)carve((size_t)NBLK * 4);
    unsigned short* srcu      = (unsigned short*)carve((size_t)N_EDGES * 2);
    unsigned short* dstu      = (unsigned short*)carve((size_t)N_EDGES * 2);
    unsigned short* rank      = (unsigned short*)carve((size_t)N_EDGES * 2);
    unsigned short* csr_src   = (unsigned short*)carve((size_t)N_EDGES * 2);
    unsigned short* xb        = (unsigned short*)carve((size_t)FEAT_ELEMS * 2);
    unsigned short* h         = (unsigned short*)carve((size_t)FEAT_ELEMS * 2);

    // 7 launches (was 11): prolog, count+convert, blocksum, offsets+apply,
    // fill, fused layer 1, fused layer 2.
    prolog_kernel<<<NBLK + 2, 256, 0, stream>>>((const unsigned int*)ei,
                                                (const unsigned int*)x, flagE, flagF, cnt);
    count_convert_kernel<<<EGRID + CGRID, 256, 0, stream>>>(ei, x, flagE, flagF, cnt,
                                                            srcu, dstu, rank, xb);
    scan_blocksum_kernel<<<NBLK, 256, 0, stream>>>(cnt, blockSums);
    scan_apply_kernel<<<NBLK, 256, 0, stream>>>(cnt, blockSums, row_ptr, dinv);
    fill_direct_kernel<<<EGRID, 256, 0, stream>>>(dstu, srcu, rank, row_ptr, csr_src);

    // layer 1: h = relu((A_hat @ x) @ W1 + b1), bf16 out
    fused_layer_kernel<<<GGRID, 256, 0, stream>>>(xb, row_ptr, csr_src, dinv,
                                                  W1, b1, flagF, h, 1);
    // layer 2: out = relu((A_hat @ h) @ W2 + b2), dtype follows input
    fused_layer_kernel<<<GGRID, 256, 0, stream>>>(h, row_ptr, csr_src, dinv,
                                                  W2, b2, flagF, d_out, 2);
}

// Round 2
// 217.426 us; speedup vs baseline: 1.0604x; 1.0604x over previous
//
#include <hip/hip_runtime.h>

#define N_NODES 50000
#define N_EDGES 800000
#define DIM 96
#define FEAT_ELEMS (N_NODES * DIM)
#define NBLK 196   // ceil(50000/256)
#define EGRID 3125 // 800000/256
#define CGRID 4688 // ceil(FEAT_ELEMS/4/256)
#define WGRID 10   // 2 weight matrices x 5 blocks (1152 frags each)
#define AGRID 3125 // ceil(50000*16/256)
#define GGRID 782  // ceil(50000/64)

typedef __attribute__((ext_vector_type(8))) short short8;   // 8 bf16 (4 VGPRs)
typedef __attribute__((ext_vector_type(4))) float float4v;  // 4 fp32 acc

// ---------------------------------------------------------------------------
// bf16 helpers via raw bit ops
// ---------------------------------------------------------------------------
__device__ __forceinline__ float bf16_to_f32(unsigned short u) {
    unsigned int w = ((unsigned int)u) << 16;
    float f;
    __builtin_memcpy(&f, &w, 4);
    return f;
}
__device__ __forceinline__ unsigned short f32_to_bf16_rne(float f) {
    unsigned int w;
    __builtin_memcpy(&w, &f, 4);
    unsigned int r = (w + 0x7FFFu + ((w >> 16) & 1u)) >> 16;
    return (unsigned short)r;
}
__device__ __forceinline__ unsigned int pack_bf16x2(float lo, float hi) {
    return (unsigned int)f32_to_bf16_rne(lo) | ((unsigned int)f32_to_bf16_rne(hi) << 16);
}

__device__ __forceinline__ int edge_at(const void* ep, int is64, int idx) {
    if (is64) return (int)((const long long*)ep)[idx];
    return ((const int*)ep)[idx];
}

// ---------------------------------------------------------------------------
// prolog: blocks [0,NBLK) zero cnt; block NBLK detects edge dtype (int64 =>
// odd 32-bit words all zero => flagE=1); block NBLK+1 detects float dtype of
// x (bf16 => bits14..7 is a N(0,1) bf16 exponent in [100,135] => flagF=1).
// ---------------------------------------------------------------------------
__global__ __launch_bounds__(256) void prolog_kernel(const unsigned int* edges,
                                                     const unsigned int* x,
                                                     int* flagE, int* flagF, int* cnt) {
    __shared__ unsigned int sh[256];
    int t = threadIdx.x;
    int b = blockIdx.x;
    if (b < NBLK) {
        int i = b * 256 + t;
        if (i < N_NODES) cnt[i] = 0;
        return;
    }
    if (b == NBLK) {
        if (t < 64) {
            unsigned int acc = 0;
            for (int k = 0; k < 4; ++k) {
                int idx = t * 4 + k;           // 0..255
                int pos = 1 + 2 * idx * 3109;  // odd words, max 1,585,591 < 1.6M
                acc |= edges[pos];
            }
            sh[t] = acc;
        }
        __syncthreads();
        if (t == 0) {
            unsigned int a = 0;
            for (int i = 0; i < 64; ++i) a |= sh[i];
            *flagE = (a == 0u) ? 1 : 0;
        }
        return;
    }
    // b == NBLK+1: feature dtype
    unsigned int w = x[t * 9000];  // max 2,295,000 < 2.4M words (bf16 interp)
    unsigned int e = (w >> 7) & 0xFFu;
    sh[t] = (e >= 100u && e <= 135u) ? 1u : 0u;
    __syncthreads();
    if (t == 0) {
        int c = 0;
        for (int i = 0; i < 256; ++i) c += (int)sh[i];
        *flagF = (c >= 128) ? 1 : 0;
    }
}

// ---------------------------------------------------------------------------
// fused prep: blocks [0,EGRID) count+compact+rank; [EGRID,EGRID+CGRID)
// convert x -> bf16; [EGRID+CGRID, +WGRID) build B-fragment-swizzled copies
// of W1/W2 in GLOBAL memory (once, instead of per-GEMM-block). All three
// depend only on prolog output. Frag f=(kt*6+nt)*64+lane holds
// W[kt*32+(lane>>4)*8+j][nt*16+(lane&15)], j=0..7 (verified m89/m91/m120).
// ---------------------------------------------------------------------------
__global__ __launch_bounds__(256) void count_convert_kernel(const void* __restrict__ edges,
                                                            const void* __restrict__ x,
                                                            const void* __restrict__ W1,
                                                            const void* __restrict__ W2,
                                                            const int* __restrict__ flagE,
                                                            const int* __restrict__ flagF,
                                                            int* __restrict__ cnt,
                                                            unsigned short* __restrict__ srcu,
                                                            unsigned short* __restrict__ dstu,
                                                            unsigned short* __restrict__ rank,
                                                            unsigned short* __restrict__ xb,
                                                            unsigned short* __restrict__ wsw1,
                                                            unsigned short* __restrict__ wsw2) {
    int b = blockIdx.x;
    if (b < EGRID) {
        int e = b * 256 + threadIdx.x;  // EGRID*256 == N_EDGES exactly
        int is64 = *flagE;
        int s = edge_at(edges, is64, e);
        int d = edge_at(edges, is64, N_EDGES + e);
        srcu[e] = (unsigned short)s;
        dstu[e] = (unsigned short)d;
        rank[e] = (unsigned short)atomicAdd(&cnt[d], 1);
        return;
    }
    if (b < EGRID + CGRID) {
        int i4 = ((b - EGRID) * 256 + threadIdx.x) * 4;
        if (i4 >= FEAT_ELEMS) return;
        int isbf16 = *flagF;
        ushort4 o;
        if (isbf16) {
            o = *(const ushort4*)((const unsigned short*)x + i4);
        } else {
            float4 v = *(const float4*)((const float*)x + i4);
            o.x = f32_to_bf16_rne(v.x);
            o.y = f32_to_bf16_rne(v.y);
            o.z = f32_to_bf16_rne(v.z);
            o.w = f32_to_bf16_rne(v.w);
        }
        *(ushort4*)(xb + i4) = o;
        return;
    }
    // weight swizzle build
    int wi = b - EGRID - CGRID;          // 0..9
    int which = wi / 5;                  // 0 -> W1, 1 -> W2
    int f = (wi - which * 5) * 256 + threadIdx.x;
    if (f >= 1152) return;
    const void* Wp = which ? W2 : W1;
    unsigned short* Op = which ? wsw2 : wsw1;
    int wBf16 = *flagF;
    int kt = f / 384;
    int rem = f - kt * 384;
    int nt = rem >> 6;
    int ln64 = rem & 63;
    int q = ln64 >> 4, ln = ln64 & 15;
    int k0 = kt * 32 + q * 8;
    int n = nt * 16 + ln;
    unsigned short e[8];
    if (wBf16) {
        const unsigned short* Wh = (const unsigned short*)Wp;
        #pragma unroll
        for (int j = 0; j < 8; ++j) e[j] = Wh[(k0 + j) * DIM + n];
    } else {
        const float* Wf = (const float*)Wp;
        #pragma unroll
        for (int j = 0; j < 8; ++j) e[j] = f32_to_bf16_rne(Wf[(k0 + j) * DIM + n]);
    }
    uint4 pk;
    pk.x = (unsigned int)e[0] | ((unsigned int)e[1] << 16);
    pk.y = (unsigned int)e[2] | ((unsigned int)e[3] << 16);
    pk.z = (unsigned int)e[4] | ((unsigned int)e[5] << 16);
    pk.w = (unsigned int)e[6] | ((unsigned int)e[7] << 16);
    *(uint4*)&Op[f * 8] = pk;
}

// ---------------------------------------------------------------------------
// scan phase 1: per-block sums of cnt
// ---------------------------------------------------------------------------
__global__ __launch_bounds__(256) void scan_blocksum_kernel(const int* cnt, int* blockSums) {
    __shared__ int sh[256];
    int i = blockIdx.x * 256 + threadIdx.x;
    sh[threadIdx.x] = (i < N_NODES) ? cnt[i] : 0;
    __syncthreads();
    for (int off = 128; off > 0; off >>= 1) {
        if (threadIdx.x < off) sh[threadIdx.x] += sh[threadIdx.x + off];
        __syncthreads();
    }
    if (threadIdx.x == 0) blockSums[blockIdx.x] = sh[0];
}

// ---------------------------------------------------------------------------
// scan phase 2 (merged offsets+apply): every block redundantly scans the 196
// block sums in LDS (cheap), derives its own exclusive offset, then scans its
// 256 cnt entries -> row_ptr (+ dinv). Block 0 thread 0 writes the total.
// ---------------------------------------------------------------------------
__global__ __launch_bounds__(256) void scan_apply_kernel(const int* __restrict__ cnt,
                                                         const int* __restrict__ blockSums,
                                                         int* __restrict__ row_ptr,
                                                         float* __restrict__ dinv) {
    __shared__ int sb[256];
    __shared__ int sh[256];
    int t = threadIdx.x;
    sb[t] = (t < NBLK) ? blockSums[t] : 0;
    __syncthreads();
    for (int off = 1; off < 256; off <<= 1) {
        int u = (t >= off) ? sb[t - off] : 0;
        __syncthreads();
        sb[t] += u;
        __syncthreads();
    }
    int b = blockIdx.x;
    int blockOff = (b == 0) ? 0 : sb[b - 1];  // exclusive prefix of this block
    if (b == 0 && t == 0) row_ptr[N_NODES] = sb[NBLK - 1];

    int i = b * 256 + t;
    int c = (i < N_NODES) ? cnt[i] : 0;
    sh[t] = c;
    __syncthreads();
    for (int off = 1; off < 256; off <<= 1) {
        int u = (t >= off) ? sh[t - off] : 0;
        __syncthreads();
        sh[t] += u;
        __syncthreads();
    }
    if (i < N_NODES) {
        row_ptr[i] = sh[t] - c + blockOff;
        dinv[i]    = rsqrtf((float)(c + 1));  // +1 self-loop
    }
}

// ---------------------------------------------------------------------------
// fill (rank-based direct scatter, NO atomics). Also precomputes per-edge
// weight dinv[s]*dinv[d] in fp32 (identical arithmetic to computing it in
// the gather) so the gather's dependent chain is csr -> feat, depth 2.
// ---------------------------------------------------------------------------
__global__ __launch_bounds__(256) void fill_direct_kernel(const unsigned short* __restrict__ dstu,
                                                          const unsigned short* __restrict__ srcu,
                                                          const unsigned short* __restrict__ rank,
                                                          const int* __restrict__ row_ptr,
                                                          const float* __restrict__ dinv,
                                                          unsigned short* __restrict__ csr_src,
                                                          float* __restrict__ csr_w) {
    int e = blockIdx.x * 256 + threadIdx.x;
    if (e >= N_EDGES) return;
    int d = dstu[e];
    int s = srcu[e];
    int pos = row_ptr[d] + (int)rank[e];
    csr_src[pos] = (unsigned short)s;
    csr_w[pos]   = dinv[s] * dinv[d];
}

// ---------------------------------------------------------------------------
// Gather-aggregate (bf16 feat, fp32 accum, bf16 out): 16 lanes per node,
// 6 dims per lane (3x ushort2), 800k threads, no LDS -> full occupancy.
// 4-edge unroll: 4 independent csr->feat chains in flight per iteration.
// ---------------------------------------------------------------------------
__global__ __launch_bounds__(256) void gather_kernel(const unsigned short* __restrict__ feat,
                                                     const int* __restrict__ row_ptr,
                                                     const unsigned short* __restrict__ csr_src,
                                                     const float* __restrict__ csr_w,
                                                     const float* __restrict__ dinv,
                                                     unsigned short* __restrict__ aggb) {
    int gid = blockIdx.x * 256 + threadIdx.x;
    int g = gid >> 4;
    int l = gid & 15;
    if (g >= N_NODES) return;
    float di = dinv[g];
    int gb = g * DIM + l * 2;
    ushort2 sv0 = *(const ushort2*)&feat[gb];
    ushort2 sv1 = *(const ushort2*)&feat[gb + 32];
    ushort2 sv2 = *(const ushort2*)&feat[gb + 64];
    float wself = di * di;
    float a0 = wself * bf16_to_f32(sv0.x), a1 = wself * bf16_to_f32(sv0.y);
    float a2 = wself * bf16_to_f32(sv1.x), a3 = wself * bf16_to_f32(sv1.y);
    float a4 = wself * bf16_to_f32(sv2.x), a5 = wself * bf16_to_f32(sv2.y);
    int e = row_ptr[g], e1 = row_ptr[g + 1];
    for (; e + 4 <= e1; e += 4) {
        int s0 = csr_src[e + 0];
        int s1 = csr_src[e + 1];
        int s2 = csr_src[e + 2];
        int s3 = csr_src[e + 3];
        float w0 = csr_w[e + 0];
        float w1 = csr_w[e + 1];
        float w2 = csr_w[e + 2];
        float w3 = csr_w[e + 3];
        int b0 = s0 * DIM + l * 2;
        int b1 = s1 * DIM + l * 2;
        int b2 = s2 * DIM + l * 2;
        int b3 = s3 * DIM + l * 2;
        ushort2 p0 = *(const ushort2*)&feat[b0];
        ushort2 p1 = *(const ushort2*)&feat[b0 + 32];
        ushort2 p2 = *(const ushort2*)&feat[b0 + 64];
        ushort2 q0 = *(const ushort2*)&feat[b1];
        ushort2 q1 = *(const ushort2*)&feat[b1 + 32];
        ushort2 q2 = *(const ushort2*)&feat[b1 + 64];
        ushort2 r0 = *(const ushort2*)&feat[b2];
        ushort2 r1 = *(const ushort2*)&feat[b2 + 32];
        ushort2 r2 = *(const ushort2*)&feat[b2 + 64];
        ushort2 t0 = *(const ushort2*)&feat[b3];
        ushort2 t1 = *(const ushort2*)&feat[b3 + 32];
        ushort2 t2 = *(const ushort2*)&feat[b3 + 64];
        a0 = fmaf(w0, bf16_to_f32(p0.x), a0);  a1 = fmaf(w0, bf16_to_f32(p0.y), a1);
        a2 = fmaf(w0, bf16_to_f32(p1.x), a2);  a3 = fmaf(w0, bf16_to_f32(p1.y), a3);
        a4 = fmaf(w0, bf16_to_f32(p2.x), a4);  a5 = fmaf(w0, bf16_to_f32(p2.y), a5);
        a0 = fmaf(w1, bf16_to_f32(q0.x), a0);  a1 = fmaf(w1, bf16_to_f32(q0.y), a1);
        a2 = fmaf(w1, bf16_to_f32(q1.x), a2);  a3 = fmaf(w1, bf16_to_f32(q1.y), a3);
        a4 = fmaf(w1, bf16_to_f32(q2.x), a4);  a5 = fmaf(w1, bf16_to_f32(q2.y), a5);
        a0 = fmaf(w2, bf16_to_f32(r0.x), a0);  a1 = fmaf(w2, bf16_to_f32(r0.y), a1);
        a2 = fmaf(w2, bf16_to_f32(r1.x), a2);  a3 = fmaf(w2, bf16_to_f32(r1.y), a3);
        a4 = fmaf(w2, bf16_to_f32(r2.x), a4);  a5 = fmaf(w2, bf16_to_f32(r2.y), a5);
        a0 = fmaf(w3, bf16_to_f32(t0.x), a0);  a1 = fmaf(w3, bf16_to_f32(t0.y), a1);
        a2 = fmaf(w3, bf16_to_f32(t1.x), a2);  a3 = fmaf(w3, bf16_to_f32(t1.y), a3);
        a4 = fmaf(w3, bf16_to_f32(t2.x), a4);  a5 = fmaf(w3, bf16_to_f32(t2.y), a5);
    }
    for (; e < e1; ++e) {
        int s = csr_src[e];
        float w = csr_w[e];
        int b0 = s * DIM + l * 2;
        ushort2 p0 = *(const ushort2*)&feat[b0];
        ushort2 p1 = *(const ushort2*)&feat[b0 + 32];
        ushort2 p2 = *(const ushort2*)&feat[b0 + 64];
        a0 = fmaf(w, bf16_to_f32(p0.x), a0);  a1 = fmaf(w, bf16_to_f32(p0.y), a1);
        a2 = fmaf(w, bf16_to_f32(p1.x), a2);  a3 = fmaf(w, bf16_to_f32(p1.y), a3);
        a4 = fmaf(w, bf16_to_f32(p2.x), a4);  a5 = fmaf(w, bf16_to_f32(p2.y), a5);
    }
    *(unsigned int*)&aggb[gb]      = pack_bf16x2(a0, a1);
    *(unsigned int*)&aggb[gb + 32] = pack_bf16x2(a2, a3);
    *(unsigned int*)&aggb[gb + 64] = pack_bf16x2(a4, a5);
}

// ---------------------------------------------------------------------------
// MFMA GEMM + bias + ReLU, NO LDS / NO syncs: out[M,96] = relu(A @ W + b).
// A bf16 [N_NODES,96]; Wsw is the pre-swizzled B-fragment table in global
// (18 KB, L2-broadcast across all blocks). mfma_f32_16x16x32_bf16, K=3x32.
// 256 thr = 4 waves x 16 rows = 64 rows/blk. A-frag: lane ln reads row
// m0+ln, 16B chunk quad*8 at col kt*32 -> per row per kt the 4 quads form
// one contiguous 64B line (coalesced). C/D: col=lane&15, row=(lane>>4)*4+reg.
// outMode: 0=fp32, 1=bf16, 2=follow flagF
// ---------------------------------------------------------------------------
__global__ __launch_bounds__(256) void gemm_mfma_kernel(const unsigned short* __restrict__ A,
                                                        const unsigned short* __restrict__ Wsw,
                                                        const void* __restrict__ bias,
                                                        const int* __restrict__ flagF,
                                                        void* __restrict__ out, int outMode) {
    int wBf16 = *flagF;
    int outBf16 = (outMode == 2) ? wBf16 : outMode;
    int t = threadIdx.x;
    int wave = t >> 6;
    int lane = t & 63;
    int quad = lane >> 4, ln = lane & 15;
    int m0 = blockIdx.x * 64 + wave * 16;
    int arow = m0 + ln;
    bool arowok = (arow < N_NODES);

    float4v acc[6];
    #pragma unroll
    for (int nt = 0; nt < 6; ++nt) acc[nt] = (float4v){0.f, 0.f, 0.f, 0.f};

    #pragma unroll
    for (int kt = 0; kt < 3; ++kt) {
        short8 af;
        if (arowok) {
            af = *(const short8*)&A[arow * DIM + kt * 32 + quad * 8];
        } else {
            af = (short8){0, 0, 0, 0, 0, 0, 0, 0};
        }
        #pragma unroll
        for (int nt = 0; nt < 6; ++nt) {
            short8 bf = *(const short8*)&Wsw[((kt * 6 + nt) * 64 + lane) * 8];
            acc[nt] = __builtin_amdgcn_mfma_f32_16x16x32_bf16(af, bf, acc[nt], 0, 0, 0);
        }
    }

    // epilogue: C/D col = ln, row = quad*4 + reg; bias straight from global
    #pragma unroll
    for (int nt = 0; nt < 6; ++nt) {
        int n = nt * 16 + ln;
        float bv = wBf16 ? bf16_to_f32(((const unsigned short*)bias)[n])
                         : ((const float*)bias)[n];
        #pragma unroll
        for (int reg = 0; reg < 4; ++reg) {
            int row = m0 + quad * 4 + reg;
            if (row >= N_NODES) continue;
            float v = fmaxf(acc[nt][reg] + bv, 0.0f);
            if (outBf16) ((unsigned short*)out)[row * DIM + n] = f32_to_bf16_rne(v);
            else         ((float*)out)[row * DIM + n] = v;
        }
    }
}

// ---------------------------------------------------------------------------
extern "C" void kernel_launch(void* const* d_in, const int* in_sizes, int n_in,
                              void* d_out, int out_size, void* d_ws, size_t ws_size,
                              hipStream_t stream) {
    const void* x  = d_in[0];
    const void* ei = d_in[1];
    const void* W1 = d_in[2];
    const void* b1 = d_in[3];
    const void* W2 = d_in[4];
    const void* b2 = d_in[5];

    char* base = (char*)d_ws;
    size_t off = 0;
    auto carve = [&](size_t bytes) -> void* {
        void* p = base + off;
        off += (bytes + 255) & ~(size_t)255;
        return p;
    };
    int*            flagE     = (int*)carve(4);
    int*            flagF     = (int*)carve(4);
    int*            cnt       = (int*)carve((size_t)N_NODES * 4);
    int*            row_ptr   = (int*)carve((size_t)(N_NODES + 1) * 4);
    float*          dinv      = (float*)carve((size_t)N_NODES * 4);
    int*            blockSums = (int*)carve((size_t)NBLK * 4);
    unsigned short* srcu      = (unsigned short*)carve((size_t)N_EDGES * 2);
    unsigned short* dstu      = (unsigned short*)carve((size_t)N_EDGES * 2);
    unsigned short* rank      = (unsigned short*)carve((size_t)N_EDGES * 2);
    unsigned short* csr_src   = (unsigned short*)carve((size_t)N_EDGES * 2);
    float*          csr_w     = (float*)carve((size_t)N_EDGES * 4);
    unsigned short* wsw1      = (unsigned short*)carve((size_t)1152 * 8 * 2);
    unsigned short* wsw2      = (unsigned short*)carve((size_t)1152 * 8 * 2);
    unsigned short* aggb      = (unsigned short*)carve((size_t)FEAT_ELEMS * 2);
    unsigned short* xb        = (unsigned short*)carve((size_t)FEAT_ELEMS * 2);
    unsigned short* h         = (unsigned short*)carve((size_t)FEAT_ELEMS * 2);

    // 9 launches: prolog, count+convert+wswizzle, blocksum, offsets+apply,
    // fill(+edge weights), gather, gemm, gather, gemm.
    prolog_kernel<<<NBLK + 2, 256, 0, stream>>>((const unsigned int*)ei,
                                                (const unsigned int*)x, flagE, flagF, cnt);
    count_convert_kernel<<<EGRID + CGRID + WGRID, 256, 0, stream>>>(
        ei, x, W1, W2, flagE, flagF, cnt, srcu, dstu, rank, xb, wsw1, wsw2);
    scan_blocksum_kernel<<<NBLK, 256, 0, stream>>>(cnt, blockSums);
    scan_apply_kernel<<<NBLK, 256, 0, stream>>>(cnt, blockSums, row_ptr, dinv);
    fill_direct_kernel<<<EGRID, 256, 0, stream>>>(dstu, srcu, rank, row_ptr, dinv,
                                                  csr_src, csr_w);

    // layer 1: aggb = A_hat @ x ; h = relu(aggb @ W1 + b1), bf16 out
    gather_kernel<<<AGRID, 256, 0, stream>>>(xb, row_ptr, csr_src, csr_w, dinv, aggb);
    gemm_mfma_kernel<<<GGRID, 256, 0, stream>>>(aggb, wsw1, b1, flagF, h, 1);

    // layer 2: aggb = A_hat @ h ; out = relu(aggb @ W2 + b2), dtype follows input
    gather_kernel<<<AGRID, 256, 0, stream>>>(h, row_ptr, csr_src, csr_w, dinv, aggb);
    gemm_mfma_kernel<<<GGRID, 256, 0, stream>>>(aggb, wsw2, b2, flagF, d_out, 2);
}